// Round 6
// baseline (214.693 us; speedup 1.0000x reference)
//
#include <hip/hip_runtime.h>
#include <hip/hip_bf16.h>

// Problem shape (fixed by setup_inputs): B=8, Q=2048 -> N=16384 rows,
// D=1024, Dp=256, K=2048 prototypes.
#define N_ROWS 16384
#define DIM    1024
#define DP     256
#define NPROTO 2048

typedef float f32x4 __attribute__((ext_vector_type(4)));
typedef short s16x8 __attribute__((ext_vector_type(8)));
typedef short s16x4 __attribute__((ext_vector_type(4)));

__device__ __forceinline__ unsigned short f2bf(float f) {
  __hip_bfloat16 h = __float2bfloat16(f);   // RNE; compiler may pack cvt
  return __builtin_bit_cast(unsigned short, h);
}

// ---- fused prep: projT[j][d]=bf16(proj[d][j]); Pb=bf16(P); pp=rowsum(P^2) ----
__global__ void k_prep(const float* __restrict__ proj,
                       const float* __restrict__ P,
                       unsigned short* __restrict__ projT,
                       unsigned short* __restrict__ Pb,
                       float* __restrict__ pp) {
  int b = blockIdx.x;
  if (b < (DIM * DP) / 256) {
    int t = b * 256 + threadIdx.x;          // t = j*1024 + d, coalesced writes
    int j = t >> 10;
    int d = t & 1023;
    projT[t] = f2bf(proj[(size_t)d * DP + j]);
  } else {
    int k = b - (DIM * DP) / 256;
    int d = threadIdx.x;                    // 256 threads = Dp
    float v = P[(size_t)k * DP + d];
    Pb[(size_t)k * DP + d] = f2bf(v);
    float s = v * v;
#pragma unroll
    for (int o = 1; o < 64; o <<= 1) s += __shfl_xor(s, o, 64);
    __shared__ float ws4[4];
    if ((threadIdx.x & 63) == 0) ws4[threadIdx.x >> 6] = s;
    __syncthreads();
    if (threadIdx.x == 0) pp[k] = ws4[0] + ws4[1] + ws4[2] + ws4[3];
  }
}

// ---- FUSED: per block (32 rows), 256 threads = 4 waves, 2 blocks/CU:
//   phase 1: Z[32][256] = normalize_rows((X - mean) @ proj)  -> LDS (bf16)
//   phase 2: out[32][2048] = -sqrt(max(1 + pp - 2 * Z @ Pb^T, 0))
// Grid 512 blocks -> 2/CU (decoupled barriers; stalls overlap across blocks).
// LDS plan (bytes, total 59,008 -> 2 blocks/CU):
//   [0     , 16896)  Zs   [32][264] bf16   (stride 132 banks = 4 mod 32 -> 2-way, free)
//   [16896 , 17024)  invs [32]      f32
//   [17024 , 17536)  rowsq[4][32]   f32
//   [17536 , 59008)  staging union, LD=36 (18 banks -> 16 lanes conflict-free b128):
//        phase1: As[2][32][36] (4608) + Bs[2][256][36] (36864)
//        phase2: Ps[2][256][36] (36864)
__global__ __launch_bounds__(256, 2)
void k_fused(const float* __restrict__ X, const float* __restrict__ mean,
             const unsigned short* __restrict__ projT,
             const unsigned short* __restrict__ Pb,
             const float* __restrict__ pp, float* __restrict__ out) {
  __shared__ __align__(16) unsigned char smem[59008];
  auto Zs    = (unsigned short(*)[264])(smem);                    // [32][264]
  auto invs  = (float*)(smem + 16896);                            // [32]
  auto rowsq = (float(*)[32])(smem + 17024);                      // [4][32]
  auto As    = (unsigned short(*)[32][36])(smem + 17536);         // [2][32][36]
  auto Bs    = (unsigned short(*)[256][36])(smem + 22144);        // [2][256][36]
  auto Ps    = (unsigned short(*)[256][36])(smem + 17536);        // [2][256][36]

  const int tid  = threadIdx.x;
  const int lane = tid & 63;
  const int wv   = tid >> 6;        // wave id 0..3
  const int l15  = lane & 15;
  const int lhi  = lane >> 4;
  const int rb   = blockIdx.x * 32;

  // phase-1 staging coords (per thread):
  //  A: 32 rows x 32 f32 = 256 f32x4 chunks -> 1/thread
  //  B: 256 rows x 32 bf16 = 1024 s16x8 chunks -> 4/thread
  const int arow = tid >> 3;             // [0,32)
  const int ach4 = (tid & 7) * 4;
  const int brow = tid >> 2;             // [0,64), chunks at +0/64/128/192
  const int bch8 = (tid & 3) * 8;
  const float* xbase = X + (size_t)(rb + arow) * DIM + ach4;
  const float* mbase = mean + ach4;
  const unsigned short* pjbase = projT + (size_t)brow * DIM + bch8;

  // phase-2 staging coords: 256 rows x 32 bf16 = 1024 s16x8 -> 4/thread
  const int srow = tid >> 2;             // [0,64), chunks at +0/64/128/192
  const int sch8 = (tid & 3) * 8;

  // ================= phase 1 =================
  f32x4 acc[2][4];
#pragma unroll
  for (int mf = 0; mf < 2; ++mf)
#pragma unroll
    for (int nf = 0; nf < 4; ++nf) acc[mf][nf] = (f32x4)0.0f;

  f32x4 xr, mr;
  s16x8 br[4];

#define P1_ISSUE(KB)                                                         \
  {                                                                          \
    xr = *(const f32x4*)(xbase + (KB));                                      \
    mr = *(const f32x4*)(mbase + (KB));                                      \
    _Pragma("unroll")                                                        \
    for (int i = 0; i < 4; ++i)                                              \
      br[i] = *(const s16x8*)(pjbase + (size_t)i * 64 * DIM + (KB));         \
  }

#define P1_WRITE(CUR)                                                        \
  {                                                                          \
    f32x4 c = xr - mr;                                                       \
    s16x4 v;                                                                 \
    v[0] = (short)f2bf(c[0]); v[1] = (short)f2bf(c[1]);                      \
    v[2] = (short)f2bf(c[2]); v[3] = (short)f2bf(c[3]);                      \
    *(s16x4*)(&As[CUR][arow][ach4]) = v;                                     \
    _Pragma("unroll")                                                        \
    for (int i = 0; i < 4; ++i)                                              \
      *(s16x8*)(&Bs[CUR][brow + i * 64][bch8]) = br[i];                      \
  }

#define P1_COMPUTE(CUR)                                                      \
  {                                                                          \
    int k0 = lhi * 8;                                                        \
    s16x8 a[2], b[4];                                                        \
    _Pragma("unroll")                                                        \
    for (int mf = 0; mf < 2; ++mf)                                           \
      a[mf] = *(const s16x8*)(&As[CUR][mf * 16 + l15][k0]);                  \
    _Pragma("unroll")                                                        \
    for (int nf = 0; nf < 4; ++nf)                                           \
      b[nf] = *(const s16x8*)(&Bs[CUR][wv * 64 + nf * 16 + l15][k0]);        \
    _Pragma("unroll")                                                        \
    for (int mf = 0; mf < 2; ++mf)                                           \
      _Pragma("unroll")                                                      \
      for (int nf = 0; nf < 4; ++nf)                                         \
        acc[mf][nf] = __builtin_amdgcn_mfma_f32_16x16x32_bf16(               \
            a[mf], b[nf], acc[mf][nf], 0, 0, 0);                             \
  }

  P1_ISSUE(0);
#pragma unroll 2
  for (int t = 0; t < DIM / 32; ++t) {
    const int cur = t & 1;
    P1_WRITE(cur);
    if (t < DIM / 32 - 1) P1_ISSUE((t + 1) * 32);
    __syncthreads();
    P1_COMPUTE(cur);
  }
#undef P1_ISSUE
#undef P1_WRITE
#undef P1_COMPUTE

  // issue phase-2 step-0 global loads NOW (latency hides under the epilogue)
  s16x8 pr[4];
#pragma unroll
  for (int i = 0; i < 4; ++i)
    pr[i] = *(const s16x8*)(Pb + (size_t)(srow + i * 64) * DP + sch8);

  // ---- phase-1 epilogue: row norms + normalized Z -> LDS ----
#pragma unroll
  for (int mf = 0; mf < 2; ++mf)
#pragma unroll
    for (int r = 0; r < 4; ++r) {
      float s = 0.0f;
#pragma unroll
      for (int nf = 0; nf < 4; ++nf) s += acc[mf][nf][r] * acc[mf][nf][r];
#pragma unroll
      for (int o = 1; o < 16; o <<= 1) s += __shfl_xor(s, o, 16);
      if (l15 == 0) rowsq[wv][mf * 16 + lhi * 4 + r] = s;
    }
  __syncthreads();      // also: all phase-1 LDS reads complete after this
  if (tid < 32) {
    float n2 = rowsq[0][tid] + rowsq[1][tid] + rowsq[2][tid] + rowsq[3][tid];
    invs[tid] = 1.0f / fmaxf(sqrtf(n2), 1e-12f);  // F.normalize eps
  }
  __syncthreads();
#pragma unroll
  for (int mf = 0; mf < 2; ++mf)
#pragma unroll
    for (int r = 0; r < 4; ++r) {
      int row   = mf * 16 + lhi * 4 + r;
      float inv = invs[row];
#pragma unroll
      for (int nf = 0; nf < 4; ++nf)
        Zs[row][wv * 64 + nf * 16 + l15] = f2bf(acc[mf][nf][r] * inv);
    }
  // (Zs-write -> phase-2-compute ordering is covered by the step-0 barrier)

  // ================= phase 2 =================
  // 8 column-tiles of 256 protos; per tile: K = 256 in 8 steps of 32.
  // Each wave owns a 32x64 out slice per tile (acc2[2][4], 8 MFMA/step).
  for (int ct = 0; ct < 8; ++ct) {
    f32x4 acc2[2][4];
#pragma unroll
    for (int mf = 0; mf < 2; ++mf)
#pragma unroll
      for (int nf = 0; nf < 4; ++nf) acc2[mf][nf] = (f32x4)0.0f;

#pragma unroll
    for (int ks = 0; ks < 8; ++ks) {
      const int cur = ks & 1;       // (ct*8+ks)&1 == ks&1
      // write previously-issued regs into LDS
#pragma unroll
      for (int i = 0; i < 4; ++i)
        *(s16x8*)(&Ps[cur][srow + i * 64][sch8]) = pr[i];
      // issue next step's loads (cross-tile at ks==7)
      if (ks < 7) {
#pragma unroll
        for (int i = 0; i < 4; ++i)
          pr[i] = *(const s16x8*)(Pb +
              (size_t)(ct * 256 + srow + i * 64) * DP + (ks + 1) * 32 + sch8);
      } else if (ct < 7) {
#pragma unroll
        for (int i = 0; i < 4; ++i)
          pr[i] = *(const s16x8*)(Pb +
              (size_t)((ct + 1) * 256 + srow + i * 64) * DP + sch8);
      }
      __syncthreads();
      // compute: A from Zs (resident), B from Ps[cur]
      {
        s16x8 a[2], b[4];
        const int kz = ks * 32 + lhi * 8;
        const int k0 = lhi * 8;
#pragma unroll
        for (int mf = 0; mf < 2; ++mf)
          a[mf] = *(const s16x8*)(&Zs[mf * 16 + l15][kz]);
#pragma unroll
        for (int nf = 0; nf < 4; ++nf)
          b[nf] = *(const s16x8*)(&Ps[cur][wv * 64 + nf * 16 + l15][k0]);
#pragma unroll
        for (int mf = 0; mf < 2; ++mf)
#pragma unroll
          for (int nf = 0; nf < 4; ++nf)
            acc2[mf][nf] = __builtin_amdgcn_mfma_f32_16x16x32_bf16(
                a[mf], b[nf], acc2[mf][nf], 0, 0, 0);
      }
    }

    // ---- epilogue for this column tile ----
    float ppv[4];
#pragma unroll
    for (int nf = 0; nf < 4; ++nf)
      ppv[nf] = pp[ct * 256 + wv * 64 + nf * 16 + l15];
#pragma unroll
    for (int mf = 0; mf < 2; ++mf)
#pragma unroll
      for (int r = 0; r < 4; ++r) {
        int row = rb + mf * 16 + lhi * 4 + r;
#pragma unroll
        for (int nf = 0; nf < 4; ++nf) {
          int col  = ct * 256 + wv * 64 + nf * 16 + l15;
          float d2 = fmaxf(1.0f + ppv[nf] - 2.0f * acc2[mf][nf][r], 0.0f);
          out[(size_t)row * NPROTO + col] = -sqrtf(d2);
        }
      }
  }
}

extern "C" void kernel_launch(void* const* d_in, const int* in_sizes, int n_in,
                              void* d_out, int out_size, void* d_ws, size_t ws_size,
                              hipStream_t stream) {
  const float* X     = (const float*)d_in[0];  // [16384,1024]
  const float* mean  = (const float*)d_in[1];  // [1024]
  const float* proj  = (const float*)d_in[2];  // [1024,256]
  const float* proto = (const float*)d_in[3];  // [2048,256]
  float* out = (float*)d_out;                  // [16384,2048]

  char* ws = (char*)d_ws;
  // workspace layout (~1.5 MB total)
  size_t off = 0;
  unsigned short* projT = (unsigned short*)(ws + off); off += (size_t)DIM * DP * 2;    // 512 KB
  unsigned short* Pb    = (unsigned short*)(ws + off); off += (size_t)NPROTO * DP * 2; // 1 MB
  float* pp             = (float*)(ws + off);          off += (size_t)NPROTO * 4;      // 8 KB

  hipLaunchKernelGGL(k_prep, dim3((DIM * DP) / 256 + NPROTO), dim3(256), 0,
                     stream, proj, proto, projT, Pb, pp);
  hipLaunchKernelGGL(k_fused, dim3(N_ROWS / 32), dim3(256), 0, stream,
                     X, mean, projT, Pb, pp, out);
}

// Round 7
// 131.679 us; speedup vs baseline: 1.6304x; 1.6304x over previous
//
#include <hip/hip_runtime.h>
#include <hip/hip_bf16.h>

// Problem shape (fixed by setup_inputs): B=8, Q=2048 -> N=16384 rows,
// D=1024, Dp=256, K=2048 prototypes.
#define N_ROWS 16384
#define DIM    1024
#define DP     256
#define NPROTO 2048

typedef float f32x4 __attribute__((ext_vector_type(4)));
typedef short s16x8 __attribute__((ext_vector_type(8)));

__device__ __forceinline__ unsigned short f2bf(float f) {
  __hip_bfloat16 h = __float2bfloat16(f);   // RNE
  return __builtin_bit_cast(unsigned short, h);
}

// ---- fused prep: projT[j][d]=bf16(proj[d][j]); Pb=bf16(P); pp=rowsum(P^2) ----
__global__ void k_prep(const float* __restrict__ proj,
                       const float* __restrict__ P,
                       unsigned short* __restrict__ projT,
                       unsigned short* __restrict__ Pb,
                       float* __restrict__ pp) {
  int b = blockIdx.x;
  if (b < (DIM * DP) / 256) {
    int t = b * 256 + threadIdx.x;          // t = j*1024 + d, coalesced writes
    int j = t >> 10;
    int d = t & 1023;
    projT[t] = f2bf(proj[(size_t)d * DP + j]);
  } else {
    int k = b - (DIM * DP) / 256;
    int d = threadIdx.x;                    // 256 threads = Dp
    float v = P[(size_t)k * DP + d];
    Pb[(size_t)k * DP + d] = f2bf(v);
    float s = v * v;
#pragma unroll
    for (int o = 1; o < 64; o <<= 1) s += __shfl_xor(s, o, 64);
    __shared__ float ws4[4];
    if ((threadIdx.x & 63) == 0) ws4[threadIdx.x >> 6] = s;
    __syncthreads();
    if (threadIdx.x == 0) pp[k] = ws4[0] + ws4[1] + ws4[2] + ws4[3];
  }
}

// ---- FUSED, BARRIER-FREE STREAMING ----
// Block = 64 rows, 512 threads = 8 waves, grid 256 = 1 block/CU.
// Phase 1 (no LDS, no barriers): wave (rg=wv>>1, ch=wv&1) computes
//   Z[rg*16..+16][ch*128..+128] = (X - mean) @ proj, with A-fragments
//   built straight from global X (rows are wave-private) and B-fragments
//   read straight from L2-resident projT. acc in registers.
// Handoff (2 barriers): wave-local sumsq reduce + cross-half combine via
//   rowsq LDS; normalized Z (bf16) written to Zs.
// Phase 2 (no barriers): wave owns protos wv*256..+256; A from resident
//   Zs (ds_read), B straight from L2-resident Pb; 16 MFMA / 8 loads;
//   epilogue -sqrt(1+pp-2s) streams to out.
__global__ __launch_bounds__(512, 2)
void k_fused(const float* __restrict__ X, const float* __restrict__ mean,
             const unsigned short* __restrict__ projT,
             const unsigned short* __restrict__ Pb,
             const float* __restrict__ pp, float* __restrict__ out) {
  __shared__ __align__(16) unsigned short Zs[64][264];  // stride 264: 2-way max
  __shared__ float rowsq[2][64];

  const int tid  = threadIdx.x;
  const int lane = tid & 63;
  const int wv   = tid >> 6;        // wave id 0..7
  const int l15  = lane & 15;
  const int lhi  = lane >> 4;
  const int rb   = blockIdx.x * 64;

  // ================= phase 1 =================
  const int rg = wv >> 1;           // row group: rows rg*16 .. +16
  const int ch = wv & 1;            // col half:  cols ch*128 .. +128
  const float* xb = X + (size_t)(rb + rg * 16 + l15) * DIM + lhi * 8;
  const float* mb = mean + lhi * 8;
  const unsigned short* pj = projT + (size_t)(ch * 128 + l15) * DIM + lhi * 8;

  f32x4 acc1[8];
#pragma unroll
  for (int nf = 0; nf < 8; ++nf) acc1[nf] = (f32x4)0.0f;

#pragma unroll 2
  for (int kb = 0; kb < DIM; kb += 32) {
    f32x4 x0 = *(const f32x4*)(xb + kb);
    f32x4 x1 = *(const f32x4*)(xb + kb + 4);
    f32x4 m0 = *(const f32x4*)(mb + kb);
    f32x4 m1 = *(const f32x4*)(mb + kb + 4);
    s16x8 a;
    a[0] = (short)f2bf(x0[0] - m0[0]);
    a[1] = (short)f2bf(x0[1] - m0[1]);
    a[2] = (short)f2bf(x0[2] - m0[2]);
    a[3] = (short)f2bf(x0[3] - m0[3]);
    a[4] = (short)f2bf(x1[0] - m1[0]);
    a[5] = (short)f2bf(x1[1] - m1[1]);
    a[6] = (short)f2bf(x1[2] - m1[2]);
    a[7] = (short)f2bf(x1[3] - m1[3]);
#pragma unroll
    for (int nf = 0; nf < 8; ++nf) {
      s16x8 b = *(const s16x8*)(pj + (size_t)nf * 16 * DIM + kb);
      acc1[nf] = __builtin_amdgcn_mfma_f32_16x16x32_bf16(a, b, acc1[nf],
                                                         0, 0, 0);
    }
  }

  // ---- handoff: row norms (wave-local + cross-half) ----
  float rs[4];
#pragma unroll
  for (int r = 0; r < 4; ++r) {
    float s = 0.0f;
#pragma unroll
    for (int nf = 0; nf < 8; ++nf) s += acc1[nf][r] * acc1[nf][r];
#pragma unroll
    for (int o = 1; o < 16; o <<= 1) s += __shfl_xor(s, o, 16);
    rs[r] = s;
  }
  if (l15 == 0) {
#pragma unroll
    for (int r = 0; r < 4; ++r) rowsq[ch][rg * 16 + lhi * 4 + r] = rs[r];
  }
  __syncthreads();
#pragma unroll
  for (int r = 0; r < 4; ++r) {
    int gr = rg * 16 + lhi * 4 + r;
    float n2  = rowsq[0][gr] + rowsq[1][gr];
    float inv = 1.0f / fmaxf(sqrtf(n2), 1e-12f);  // F.normalize eps
#pragma unroll
    for (int nf = 0; nf < 8; ++nf)
      Zs[gr][ch * 128 + nf * 16 + l15] = f2bf(acc1[nf][r] * inv);
  }
  __syncthreads();

  // ================= phase 2 =================
  const unsigned short* pbb = Pb + (size_t)(wv * 256 + l15) * DP + lhi * 8;
  const float* ppb = pp + wv * 256;

  for (int g = 0; g < 4; ++g) {           // 4 groups of 64 protos
    f32x4 acc2[4][4];
#pragma unroll
    for (int mf = 0; mf < 4; ++mf)
#pragma unroll
      for (int nf = 0; nf < 4; ++nf) acc2[mf][nf] = (f32x4)0.0f;

#pragma unroll
    for (int kb = 0; kb < DP; kb += 32) {
      s16x8 a[4], b[4];
#pragma unroll
      for (int mf = 0; mf < 4; ++mf)
        a[mf] = *(const s16x8*)(&Zs[mf * 16 + l15][kb + lhi * 8]);
#pragma unroll
      for (int nf = 0; nf < 4; ++nf)
        b[nf] = *(const s16x8*)(pbb + (size_t)(g * 64 + nf * 16) * DP + kb);
#pragma unroll
      for (int mf = 0; mf < 4; ++mf)
#pragma unroll
        for (int nf = 0; nf < 4; ++nf)
          acc2[mf][nf] = __builtin_amdgcn_mfma_f32_16x16x32_bf16(
              a[mf], b[nf], acc2[mf][nf], 0, 0, 0);
    }

    float ppv[4];
#pragma unroll
    for (int nf = 0; nf < 4; ++nf) ppv[nf] = ppb[g * 64 + nf * 16 + l15];
#pragma unroll
    for (int mf = 0; mf < 4; ++mf)
#pragma unroll
      for (int r = 0; r < 4; ++r) {
        int row = rb + mf * 16 + lhi * 4 + r;
#pragma unroll
        for (int nf = 0; nf < 4; ++nf) {
          int col  = wv * 256 + g * 64 + nf * 16 + l15;
          float d2 = fmaxf(1.0f + ppv[nf] - 2.0f * acc2[mf][nf][r], 0.0f);
          out[(size_t)row * NPROTO + col] = -sqrtf(d2);
        }
      }
  }
}

extern "C" void kernel_launch(void* const* d_in, const int* in_sizes, int n_in,
                              void* d_out, int out_size, void* d_ws, size_t ws_size,
                              hipStream_t stream) {
  const float* X     = (const float*)d_in[0];  // [16384,1024]
  const float* mean  = (const float*)d_in[1];  // [1024]
  const float* proj  = (const float*)d_in[2];  // [1024,256]
  const float* proto = (const float*)d_in[3];  // [2048,256]
  float* out = (float*)d_out;                  // [16384,2048]

  char* ws = (char*)d_ws;
  // workspace layout (~1.5 MB total)
  size_t off = 0;
  unsigned short* projT = (unsigned short*)(ws + off); off += (size_t)DIM * DP * 2;    // 512 KB
  unsigned short* Pb    = (unsigned short*)(ws + off); off += (size_t)NPROTO * DP * 2; // 1 MB
  float* pp             = (float*)(ws + off);          off += (size_t)NPROTO * 4;      // 8 KB

  hipLaunchKernelGGL(k_prep, dim3((DIM * DP) / 256 + NPROTO), dim3(256), 0,
                     stream, proj, proto, projT, Pb, pp);
  hipLaunchKernelGGL(k_fused, dim3(N_ROWS / 64), dim3(512), 0, stream,
                     X, mean, projT, Pb, pp, out);
}